// Round 10
// baseline (994.839 us; speedup 1.0000x reference)
//
#include <hip/hip_runtime.h>

// Decoder: 2-layer graph-conv LSTM, N=4096, B=32, C=16, H=64, K=3.
// supp GEMMs: 256x256 tile, BK=64, 8 waves, m201-style 8-phase schedule,
// now with v_mfma_f32_32x32x16_bf16 (4059 FLOP/cyc/CU vs 3377 for 16x16 —
// m06/m119): same LDS traffic, same reg budget, -17% MFMA wall.
// Rectangle-preserving XCD decode. Fused bf16-MFMA gates + fp32 LSTM cell.

#define NN 4096
#define BB 32
#define HH 64

typedef __attribute__((ext_vector_type(8))) short short8;
typedef __attribute__((ext_vector_type(4))) float f32x4;
typedef __attribute__((ext_vector_type(16))) float f32x16;

#define BARRIER asm volatile("s_barrier" ::: "memory")
#define VMCNT(n) asm volatile("s_waitcnt vmcnt(" #n ")" ::: "memory")

__device__ __forceinline__ unsigned short f2bf(float f) {
  unsigned int u = __float_as_uint(f);
  u += 0x7fffu + ((u >> 16) & 1u);
  return (unsigned short)(u >> 16);
}

// ---------------- G fp32 -> bf16 (vectorized) ----------------
__global__ __launch_bounds__(256) void cvt_kernel(const float* __restrict__ in,
                                                  unsigned short* __restrict__ out,
                                                  long n4) {
  long i = (long)blockIdx.x * 256 + threadIdx.x;
  if (i >= n4) return;
  float4 v = ((const float4*)in)[i];
  ushort4 o;
  o.x = f2bf(v.x); o.y = f2bf(v.y); o.z = f2bf(v.z); o.w = f2bf(v.w);
  ((ushort4*)out)[i] = o;
}

// ---------------- zero supp0 pad cols (240..255 of each 256-col row) -------
__global__ __launch_bounds__(256) void pad_zero(unsigned short* __restrict__ supp) {
  int i = blockIdx.x * 256 + threadIdx.x;   // 262144 short8 units
  int row = i >> 1;
  int half = i & 1;
  short8 z = {};
  *(short8*)&supp[(long)row * 256 + 240 + half * 8] = z;
}

// ---------------- pack comb0^T : [2560][4096] bf16 ----------------
__global__ __launch_bounds__(256) void pack_comb0(const float* __restrict__ x,
                                                  const float* __restrict__ h,
                                                  unsigned short* __restrict__ cT) {
  __shared__ float tile[80][65];
  const int m0 = blockIdx.x * 64;
  const int b = blockIdx.y;
  const int t = threadIdx.x;
  for (int i = t; i < 64 * 16; i += 256) {
    int m = i >> 4, p = i & 15;
    tile[p][m] = x[((long)b * NN + m0 + m) * 16 + p];
  }
  for (int i = t; i < 64 * 64; i += 256) {
    int m = i >> 6, p = i & 63;
    tile[16 + p][m] = h[((long)b * NN + m0 + m) * 64 + p];
  }
  __syncthreads();
  for (int i = t; i < 80 * 64; i += 256) {
    int p = i >> 6, m = i & 63;
    cT[((long)(b * 80 + p)) * NN + m0 + m] = f2bf(tile[p][m]);
  }
}

// ---------------- pack h1 into comb1^T cols [b*128+64 ..] ----------------
__global__ __launch_bounds__(256) void pack_h1(const float* __restrict__ h,
                                               unsigned short* __restrict__ cT) {
  __shared__ float tile[64][65];
  const int m0 = blockIdx.x * 64;
  const int b = blockIdx.y;
  const int t = threadIdx.x;
  for (int i = t; i < 64 * 64; i += 256) {
    int m = i >> 6, p = i & 63;
    tile[p][m] = h[((long)b * NN + m0 + m) * 64 + p];
  }
  __syncthreads();
  for (int i = t; i < 64 * 64; i += 256) {
    int p = i >> 6, m = i & 63;
    cT[((long)(b * 128 + 64 + p)) * NN + m0 + m] = f2bf(tile[p][m]);
  }
}

// ---------------- W [KP][256] fp32 -> Wt [256][SP] bf16 (zero-pad) --------
__global__ __launch_bounds__(256) void prep_wt(const float* __restrict__ W,
                                               unsigned short* __restrict__ Wt,
                                               int KP, int SP) {
  int c = blockIdx.x;
  for (int k = threadIdx.x; k < SP; k += blockDim.x)
    Wt[(long)c * SP + k] = (k < KP) ? f2bf(W[(long)k * 256 + c]) : (unsigned short)0;
}

// ---------------- supp GEMM: 256x256, BK=64, 8 waves, 8-phase, 32x32 MFMA --
// out[b,n,k,p] = sum_m G[k][n][m] * combT[b*P+p][m]
// LDS 128 KiB = 2 dbuf x (A 32K + B 32K). Per phase: {reads(4-8 b128) +
// 1 half-tile stage} pre-barrier; {8 x mfma_32x32x16} post-barrier.
// Stage slots (t=2g): P1 Atop(t+1), P2 Abot(t+1), P3 Bbot(t+1),
// P4 Btop(t+2)+VMCNT(2), P5 Atop(t+2), P6 Abot(t+2), P7 Bbot(t+2),
// P8 Btop(t+3)+VMCNT(2). Ledger identical to R9 (HW-verified).
// Frag maps (32x32x16): A/B row|col = lane&31, k-half = lane>>5;
// C/D col = lane&31, row = (reg&3)+8*(reg>>2)+4*(lane>>5)  [m74/m101].
template <int P, int SP, int RPK>
__global__ __launch_bounds__(512, 2) void gemm_supp8(const unsigned short* __restrict__ Gb,
                                                     const unsigned short* __restrict__ BT,
                                                     unsigned short* __restrict__ supp) {
  __shared__ short lds[2][2][256 * 64];  // 128 KiB
  const int t = threadIdx.x;
  const int w = t >> 6;
  const int lane = t & 63;
  const int l31 = lane & 31;
  const int lh = lane >> 5;   // k-half selector
  const int wm = w >> 2;      // 0..1 : row half (128 rows)
  const int wn = w & 3;       // 0..3 : col band (64 cols)

  const int bid = blockIdx.x;
  const int xcd = bid & 7;
  const int rank = bid >> 3;
  const int kh = rank / RPK;
  const int jr = rank - kh * RPK;
  const int bm = xcd * 2 + (jr & 1);
  const int bc = jr >> 1;

  const short* Ag = (const short*)Gb + (long)kh * NN * NN + (long)bm * 256 * NN;
  const short* Bg = (const short*)BT + (long)bc * 256 * NN;

  // stage one row-half (128 rows x 64 k); linear LDS dest + XOR-swizzled src.
  auto stage = [&](int mat, int buf, int kt, int half) {
    const short* base = (mat ? Bg : Ag) + kt * 64;
#pragma unroll
    for (int j = 0; j < 2; ++j) {
      int L = j * 512 + t;
      int rl = L >> 3;
      int sl = L & 7;
      int r = half * 128 + rl;
      int s0 = sl ^ (r & 7);
      short* dst = &lds[buf][mat][(half * 1024 + j * 512 + w * 64) * 8];
      __builtin_amdgcn_global_load_lds(
          (const __attribute__((address_space(1))) void*)(base + (long)r * NN + s0 * 8),
          (__attribute__((address_space(3))) void*)dst, 16, 0, 0);
    }
  };

  f32x16 acc[4][2] = {};      // [m-frag 32rows][n-frag 32cols] -> 128 AGPR
  short8 a2[2][2], bfr[2][2]; // [frag][k-step within pair]

  // rdA: u = m-half (64 rows = 2 frags), kp = k-pair (2 MFMA k-steps of 16)
  auto rdA = [&](int buf, int u, int kp) {
#pragma unroll
    for (int mi = 0; mi < 2; ++mi)
#pragma unroll
      for (int kst = 0; kst < 2; ++kst) {
        int row = wm * 128 + (u * 2 + mi) * 32 + l31;
        int slot = ((kp * 2 + kst) * 2 + lh) ^ (row & 7);
        a2[mi][kst] = *(const short8*)&lds[buf][0][row * 64 + slot * 8];
      }
  };
  auto rdB = [&](int buf, int kp) {
#pragma unroll
    for (int ni = 0; ni < 2; ++ni)
#pragma unroll
      for (int kst = 0; kst < 2; ++kst) {
        int row = wn * 64 + ni * 32 + l31;
        int slot = ((kp * 2 + kst) * 2 + lh) ^ (row & 7);
        bfr[ni][kst] = *(const short8*)&lds[buf][1][row * 64 + slot * 8];
      }
  };
  auto mmac = [&](int u) {
    __builtin_amdgcn_s_setprio(1);
#pragma unroll
    for (int kst = 0; kst < 2; ++kst)
#pragma unroll
      for (int mi = 0; mi < 2; ++mi)
#pragma unroll
        for (int ni = 0; ni < 2; ++ni)
          acc[u * 2 + mi][ni] = __builtin_amdgcn_mfma_f32_32x32x16_bf16(
              a2[mi][kst], bfr[ni][kst], acc[u * 2 + mi][ni], 0, 0, 0);
    __builtin_amdgcn_s_setprio(0);
  };

  // prologue: tile0 (4 halves) -> buf0; Btop(1) -> buf1 (= steady "prev P8").
  stage(0, 0, 0, 0); stage(0, 0, 0, 1);
  stage(1, 0, 0, 0); stage(1, 0, 0, 1);
  stage(1, 1, 1, 0);
  VMCNT(2);
  BARRIER;

  for (int g = 0; g < 32; ++g) {
    const int tk = 2 * g;
    // P1: tile tk (buf0) u0,kp0
    rdB(0, 0); rdA(0, 0, 0);
    stage(0, 1, tk + 1, 0);                 // Atop(t+1)
    BARRIER; mmac(0); BARRIER;
    // P2: u1,kp0 (reuse bfr)
    rdA(0, 1, 0);
    stage(0, 1, tk + 1, 1);                 // Abot(t+1)
    BARRIER; mmac(1); BARRIER;
    // P3: u0,kp1
    rdB(0, 1); rdA(0, 0, 1);
    stage(1, 1, tk + 1, 1);                 // Bbot(t+1)
    BARRIER; mmac(0); BARRIER;
    // P4: u1,kp1
    rdA(0, 1, 1);
    if (tk + 2 < 64) { stage(1, 0, tk + 2, 0); VMCNT(2); }  // Btop(t+2)
    else             { VMCNT(0); }
    BARRIER; mmac(1); BARRIER;
    // P5: tile tk+1 (buf1) u0,kp0
    rdB(1, 0); rdA(1, 0, 0);
    if (tk + 2 < 64) stage(0, 0, tk + 2, 0);  // Atop(t+2)
    BARRIER; mmac(0); BARRIER;
    // P6: u1,kp0
    rdA(1, 1, 0);
    if (tk + 2 < 64) stage(0, 0, tk + 2, 1);  // Abot(t+2)
    BARRIER; mmac(1); BARRIER;
    // P7: u0,kp1
    rdB(1, 1); rdA(1, 0, 1);
    if (tk + 2 < 64) stage(1, 0, tk + 2, 1);  // Bbot(t+2)
    BARRIER; mmac(0); BARRIER;
    // P8: u1,kp1
    rdA(1, 1, 1);
    if (tk + 3 < 64) { stage(1, 1, tk + 3, 0); VMCNT(2); }  // Btop(t+3)
    else             { VMCNT(0); }
    BARRIER; mmac(1); BARRIER;
  }

  // Epilogue: 32x32 C/D layout (m74/m101): col=lane&31,
  // row=(reg&3)+8*(reg>>2)+4*(lane>>5). Plain stores.
#pragma unroll
  for (int mi = 0; mi < 4; ++mi) {
#pragma unroll
    for (int ni = 0; ni < 2; ++ni) {
      int ccol = bc * 256 + wn * 64 + ni * 32 + l31;
      int b = ccol / P;
      int p = ccol - b * P;
#pragma unroll
      for (int reg = 0; reg < 16; ++reg) {
        int rl = (reg & 3) + 8 * (reg >> 2) + 4 * lh;
        int n = bm * 256 + wm * 128 + mi * 32 + rl;
        supp[((long)(b * NN + n)) * SP + kh * P + p] = f2bf(acc[mi][ni][reg]);
      }
    }
  }
}

// ---------------- gates GEMM + LSTM cell, fused (32 tokens/wave) ----------
template <int SP, bool WBF, bool WH2>
__global__ __launch_bounds__(256) void gates_cell(const unsigned short* __restrict__ supp,
                                                  const unsigned short* __restrict__ Wt,
                                                  const float* __restrict__ bias,
                                                  const float* __restrict__ c_pre,
                                                  float* __restrict__ h_out,
                                                  float* __restrict__ c_out,
                                                  float* __restrict__ h_out2,
                                                  unsigned short* __restrict__ h_bf) {
  const int t = threadIdx.x;
  const int w = t >> 6;
  const int lane = t & 63;
  const int lr = lane & 15;
  const int q = lane >> 4;
  const long tok0 = (long)blockIdx.x * 128 + w * 32;
  f32x4 acc[2][16] = {};

  const short* sp0 = (const short*)supp + (tok0 + lr) * SP + q * 8;
  const short* sp1 = sp0 + 16 * SP;
  const short* wt = (const short*)Wt + (long)lr * SP + q * 8;
  for (int kk = 0; kk < SP / 32; ++kk) {
    short8 a0 = *(const short8*)(sp0 + kk * 32);
    short8 a1 = *(const short8*)(sp1 + kk * 32);
#pragma unroll
    for (int nf = 0; nf < 16; ++nf) {
      short8 b = *(const short8*)(wt + (long)nf * 16 * SP + kk * 32);
      acc[0][nf] = __builtin_amdgcn_mfma_f32_16x16x32_bf16(a0, b, acc[0][nf], 0, 0, 0);
      acc[1][nf] = __builtin_amdgcn_mfma_f32_16x16x32_bf16(a1, b, acc[1][nf], 0, 0, 0);
    }
  }
#pragma unroll
  for (int gi = 0; gi < 2; ++gi) {
#pragma unroll
    for (int i = 0; i < 4; ++i) {
      long tok = tok0 + gi * 16 + q * 4 + i;
      int bidx = (int)(tok >> 12);
      int n = (int)(tok & (NN - 1));
#pragma unroll
      for (int j = 0; j < 4; ++j) {
        int h = lr + 16 * j;
        float gi_ = acc[gi][j][i] + bias[h];
        float gf_ = acc[gi][j + 4][i] + bias[h + 64];
        float go_ = acc[gi][j + 8][i] + bias[h + 128];
        float gg_ = acc[gi][j + 12][i] + bias[h + 192];
        float cp = c_pre[tok * 64 + h];
        float ig = 1.f / (1.f + __expf(-gi_));
        float fg = 1.f / (1.f + __expf(-gf_));
        float og = 1.f / (1.f + __expf(-go_));
        float ct = fg * cp + ig * tanhf(gg_);
        float ht = og * tanhf(ct);
        c_out[tok * 64 + h] = ct;
        h_out[tok * 64 + h] = ht;
        if (WH2) h_out2[tok * 64 + h] = ht;
        if (WBF) h_bf[((long)(bidx * 128 + h)) * NN + n] = f2bf(ht);
      }
    }
  }
}

extern "C" void kernel_launch(void* const* d_in, const int* in_sizes, int n_in,
                              void* d_out, int out_size, void* d_ws, size_t ws_size,
                              hipStream_t stream) {
  const float* G  = (const float*)d_in[0];
  const float* x_t = (const float*)d_in[1];
  const float* h0 = (const float*)d_in[2];
  const float* h1 = (const float*)d_in[3];
  const float* c0 = (const float*)d_in[4];
  const float* c1 = (const float*)d_in[5];
  const float* W0 = (const float*)d_in[6];
  const float* b0 = (const float*)d_in[7];
  const float* W1 = (const float*)d_in[8];
  const float* b1 = (const float*)d_in[9];
  float* out = (float*)d_out;
  const long M = 8388608L;  // B*N*H

  char* ws = (char*)d_ws;
  unsigned short* Gb    = (unsigned short*)(ws);               // 100,663,296 B
  unsigned short* c0T   = (unsigned short*)(ws + 100663296L);  //  20,971,520 B
  unsigned short* c1T   = (unsigned short*)(ws + 121634816L);  //  33,554,432 B
  unsigned short* supp1 = (unsigned short*)(ws + 155189248L);  // 100,663,296 B
  unsigned short* supp0 = supp1;  // aliased (dead before gemm1 writes)
  unsigned short* Wt0   = (unsigned short*)(ws + 255852544L);
  unsigned short* Wt1   = (unsigned short*)(ws + 255983616L);

  // zero layer-0 supp pad cols only (4 MB instead of 64 MB memset)
  pad_zero<<<1024, 256, 0, stream>>>(supp0);

  cvt_kernel<<<49152, 256, 0, stream>>>(G, Gb, 12582912L);
  pack_comb0<<<dim3(64, 32), 256, 0, stream>>>(x_t, h0, c0T);
  pack_h1<<<dim3(64, 32), 256, 0, stream>>>(h1, c1T);
  prep_wt<<<dim3(256), 256, 0, stream>>>(W0, Wt0, 240, 256);
  prep_wt<<<dim3(256), 256, 0, stream>>>(W1, Wt1, 384, 384);

  // layer 0: 16 bm x 10 bc x 3 kh = 480 blocks; RPK = 20 ranks per kh
  gemm_supp8<80, 256, 20><<<480, 512, 0, stream>>>(Gb, c0T, supp0);
  gates_cell<256, true, false><<<1024, 256, 0, stream>>>(
      supp0, Wt0, b0, c0, out + M, out + 3 * M, nullptr, c1T);
  // layer 1: 16 bm x 16 bc x 3 kh = 768 blocks; RPK = 32
  gemm_supp8<128, 384, 32><<<768, 512, 0, stream>>>(Gb, c1T, supp1);
  gates_cell<384, false, true><<<1024, 256, 0, stream>>>(
      supp1, Wt1, b1, c1, out, out + 4 * M, out + 2 * M, nullptr);
}

// Round 11
// 922.925 us; speedup vs baseline: 1.0779x; 1.0779x over previous
//
#include <hip/hip_runtime.h>

// Decoder: 2-layer graph-conv LSTM, N=4096, B=32, C=16, H=64, K=3.
// supp GEMMs: 256x256 tile, BK=64, 8 waves, 16x16x32 MFMA, "flow" schedule:
// 2 barriers per K-tile; within a tile, ds_reads and MFMA clusters interleave
// in-order per wave (port runs under matrix pipe); stages for tile t+1 issue
// at tile-t start and drain (VMCNT 0) ~2300 cyc later at the tile boundary.
// Rectangle-preserving XCD decode. Fused bf16-MFMA gates + fp32 LSTM cell.

#define NN 4096
#define BB 32
#define HH 64

typedef __attribute__((ext_vector_type(8))) short short8;
typedef __attribute__((ext_vector_type(4))) float f32x4;

#define BARRIER asm volatile("s_barrier" ::: "memory")
#define VMCNT(n) asm volatile("s_waitcnt vmcnt(" #n ")" ::: "memory")

__device__ __forceinline__ unsigned short f2bf(float f) {
  unsigned int u = __float_as_uint(f);
  u += 0x7fffu + ((u >> 16) & 1u);
  return (unsigned short)(u >> 16);
}

// ---------------- G fp32 -> bf16 (vectorized) ----------------
__global__ __launch_bounds__(256) void cvt_kernel(const float* __restrict__ in,
                                                  unsigned short* __restrict__ out,
                                                  long n4) {
  long i = (long)blockIdx.x * 256 + threadIdx.x;
  if (i >= n4) return;
  float4 v = ((const float4*)in)[i];
  ushort4 o;
  o.x = f2bf(v.x); o.y = f2bf(v.y); o.z = f2bf(v.z); o.w = f2bf(v.w);
  ((ushort4*)out)[i] = o;
}

// ---------------- zero supp0 pad cols (240..255 of each 256-col row) -------
__global__ __launch_bounds__(256) void pad_zero(unsigned short* __restrict__ supp) {
  int i = blockIdx.x * 256 + threadIdx.x;   // 262144 short8 units
  int row = i >> 1;
  int half = i & 1;
  short8 z = {};
  *(short8*)&supp[(long)row * 256 + 240 + half * 8] = z;
}

// ---------------- pack comb0^T : [2560][4096] bf16 ----------------
__global__ __launch_bounds__(256) void pack_comb0(const float* __restrict__ x,
                                                  const float* __restrict__ h,
                                                  unsigned short* __restrict__ cT) {
  __shared__ float tile[80][65];
  const int m0 = blockIdx.x * 64;
  const int b = blockIdx.y;
  const int t = threadIdx.x;
  for (int i = t; i < 64 * 16; i += 256) {
    int m = i >> 4, p = i & 15;
    tile[p][m] = x[((long)b * NN + m0 + m) * 16 + p];
  }
  for (int i = t; i < 64 * 64; i += 256) {
    int m = i >> 6, p = i & 63;
    tile[16 + p][m] = h[((long)b * NN + m0 + m) * 64 + p];
  }
  __syncthreads();
  for (int i = t; i < 80 * 64; i += 256) {
    int p = i >> 6, m = i & 63;
    cT[((long)(b * 80 + p)) * NN + m0 + m] = f2bf(tile[p][m]);
  }
}

// ---------------- pack h1 into comb1^T cols [b*128+64 ..] ----------------
__global__ __launch_bounds__(256) void pack_h1(const float* __restrict__ h,
                                               unsigned short* __restrict__ cT) {
  __shared__ float tile[64][65];
  const int m0 = blockIdx.x * 64;
  const int b = blockIdx.y;
  const int t = threadIdx.x;
  for (int i = t; i < 64 * 64; i += 256) {
    int m = i >> 6, p = i & 63;
    tile[p][m] = h[((long)b * NN + m0 + m) * 64 + p];
  }
  __syncthreads();
  for (int i = t; i < 64 * 64; i += 256) {
    int p = i >> 6, m = i & 63;
    cT[((long)(b * 128 + 64 + p)) * NN + m0 + m] = f2bf(tile[p][m]);
  }
}

// ---------------- W [KP][256] fp32 -> Wt [256][SP] bf16 (zero-pad) --------
__global__ __launch_bounds__(256) void prep_wt(const float* __restrict__ W,
                                               unsigned short* __restrict__ Wt,
                                               int KP, int SP) {
  int c = blockIdx.x;
  for (int k = threadIdx.x; k < SP; k += blockDim.x)
    Wt[(long)c * SP + k] = (k < KP) ? f2bf(W[(long)k * 256 + c]) : (unsigned short)0;
}

// ---------------- supp GEMM: 256x256, BK=64, 8 waves, flow schedule --------
// out[b,n,k,p] = sum_m G[k][n][m] * combT[b*P+p][m]
// LDS 128 KiB = 2 dbuf x (A 32K + B 32K). Per K-tile: one inter-barrier
// window containing {all 24 ds_reads + 4 mmac clusters interleaved + 4
// half-tile stages for t+1}; VMCNT(0)+BARRIER at tile end only.
// Safety: each wave's reads of buf p are consumed (lgkm-drained by the MFMA
// data dependency) before its tile-end barrier; stages into buf p for t+2
// are issued only after that barrier. Stage->drain slack ~2300 cyc > HBM.
template <int P, int SP, int RPK>
__global__ __launch_bounds__(512, 2) void gemm_flow(const unsigned short* __restrict__ Gb,
                                                    const unsigned short* __restrict__ BT,
                                                    unsigned short* __restrict__ supp) {
  __shared__ short lds[2][2][256 * 64];  // 128 KiB
  const int t = threadIdx.x;
  const int w = t >> 6;
  const int lane = t & 63;
  const int lr = lane & 15;
  const int q = lane >> 4;
  const int wm = w >> 2;   // 0..1 : row half (128 rows)
  const int wn = w & 3;    // 0..3 : col band (64 cols)

  const int bid = blockIdx.x;
  const int xcd = bid & 7;
  const int rank = bid >> 3;
  const int kh = rank / RPK;
  const int jr = rank - kh * RPK;
  const int bm = xcd * 2 + (jr & 1);
  const int bc = jr >> 1;

  const short* Ag = (const short*)Gb + (long)kh * NN * NN + (long)bm * 256 * NN;
  const short* Bg = (const short*)BT + (long)bc * 256 * NN;

  // stage one row-half (128 rows x 64 k); linear LDS dest + XOR-swizzled src.
  auto stage = [&](int mat, int buf, int kt, int half) {
    const short* base = (mat ? Bg : Ag) + kt * 64;
#pragma unroll
    for (int j = 0; j < 2; ++j) {
      int L = j * 512 + t;
      int rl = L >> 3;
      int sl = L & 7;
      int r = half * 128 + rl;
      int s0 = sl ^ (r & 7);
      short* dst = &lds[buf][mat][(half * 1024 + j * 512 + w * 64) * 8];
      __builtin_amdgcn_global_load_lds(
          (const __attribute__((address_space(1))) void*)(base + (long)r * NN + s0 * 8),
          (__attribute__((address_space(3))) void*)dst, 16, 0, 0);
    }
  };

  f32x4 acc[8][4] = {};
  short8 a4[4], bfr[4];

  auto rdA = [&](int buf, int u, int ks) {
#pragma unroll
    for (int mi = 0; mi < 4; ++mi) {
      int row = wm * 128 + (u * 4 + mi) * 16 + lr;
      int slot = (ks * 4 + q) ^ (row & 7);
      a4[mi] = *(const short8*)&lds[buf][0][row * 64 + slot * 8];
    }
  };
  auto rdB = [&](int buf, int ks) {
#pragma unroll
    for (int ni = 0; ni < 4; ++ni) {
      int row = wn * 64 + ni * 16 + lr;
      int slot = (ks * 4 + q) ^ (row & 7);
      bfr[ni] = *(const short8*)&lds[buf][1][row * 64 + slot * 8];
    }
  };
  auto mmac = [&](int u) {
    __builtin_amdgcn_s_setprio(1);
#pragma unroll
    for (int mi = 0; mi < 4; ++mi)
#pragma unroll
      for (int ni = 0; ni < 4; ++ni)
        acc[u * 4 + mi][ni] =
            __builtin_amdgcn_mfma_f32_16x16x32_bf16(a4[mi], bfr[ni], acc[u * 4 + mi][ni], 0, 0, 0);
    __builtin_amdgcn_s_setprio(0);
  };

  // prologue: tile0 (all 4 halves) -> buf0.
  stage(0, 0, 0, 0); stage(0, 0, 0, 1);
  stage(1, 0, 0, 0); stage(1, 0, 0, 1);
  VMCNT(0);
  BARRIER;

  for (int g = 0; g < 32; ++g) {
    const int tk = 2 * g;
    // ---- tile tk (buf0); stage tile tk+1 -> buf1 ----
    rdB(0, 0); rdA(0, 0, 0);
    stage(0, 1, tk + 1, 0); stage(0, 1, tk + 1, 1);   // A(t+1)
    mmac(0);
    rdA(0, 1, 0);
    stage(1, 1, tk + 1, 0);                            // Btop(t+1)
    mmac(1);
    rdB(0, 1); rdA(0, 0, 1);
    stage(1, 1, tk + 1, 1);                            // Bbot(t+1)
    mmac(0);
    rdA(0, 1, 1);
    mmac(1);
    VMCNT(0);
    BARRIER;
    // ---- tile tk+1 (buf1); stage tile tk+2 -> buf0 ----
    rdB(1, 0); rdA(1, 0, 0);
    if (tk + 2 < 64) { stage(0, 0, tk + 2, 0); stage(0, 0, tk + 2, 1); }
    mmac(0);
    rdA(1, 1, 0);
    if (tk + 2 < 64) stage(1, 0, tk + 2, 0);
    mmac(1);
    rdB(1, 1); rdA(1, 0, 1);
    if (tk + 2 < 64) stage(1, 0, tk + 2, 1);
    mmac(0);
    rdA(1, 1, 1);
    mmac(1);
    VMCNT(0);
    BARRIER;
  }

  // Epilogue: D col=lane&15, row=(lane>>4)*4+i (verified); plain stores.
#pragma unroll
  for (int mi = 0; mi < 8; ++mi) {
#pragma unroll
    for (int ni = 0; ni < 4; ++ni) {
      int ccol = bc * 256 + wn * 64 + ni * 16 + lr;
      int b = ccol / P;
      int p = ccol - b * P;
#pragma unroll
      for (int i = 0; i < 4; ++i) {
        int n = bm * 256 + wm * 128 + mi * 16 + q * 4 + i;
        supp[((long)(b * NN + n)) * SP + kh * P + p] = f2bf(acc[mi][ni][i]);
      }
    }
  }
}

// ---------------- gates GEMM + LSTM cell, fused (32 tokens/wave) ----------
template <int SP, bool WBF, bool WH2>
__global__ __launch_bounds__(256) void gates_cell(const unsigned short* __restrict__ supp,
                                                  const unsigned short* __restrict__ Wt,
                                                  const float* __restrict__ bias,
                                                  const float* __restrict__ c_pre,
                                                  float* __restrict__ h_out,
                                                  float* __restrict__ c_out,
                                                  float* __restrict__ h_out2,
                                                  unsigned short* __restrict__ h_bf) {
  const int t = threadIdx.x;
  const int w = t >> 6;
  const int lane = t & 63;
  const int lr = lane & 15;
  const int q = lane >> 4;
  const long tok0 = (long)blockIdx.x * 128 + w * 32;
  f32x4 acc[2][16] = {};

  const short* sp0 = (const short*)supp + (tok0 + lr) * SP + q * 8;
  const short* sp1 = sp0 + 16 * SP;
  const short* wt = (const short*)Wt + (long)lr * SP + q * 8;
  for (int kk = 0; kk < SP / 32; ++kk) {
    short8 a0 = *(const short8*)(sp0 + kk * 32);
    short8 a1 = *(const short8*)(sp1 + kk * 32);
#pragma unroll
    for (int nf = 0; nf < 16; ++nf) {
      short8 b = *(const short8*)(wt + (long)nf * 16 * SP + kk * 32);
      acc[0][nf] = __builtin_amdgcn_mfma_f32_16x16x32_bf16(a0, b, acc[0][nf], 0, 0, 0);
      acc[1][nf] = __builtin_amdgcn_mfma_f32_16x16x32_bf16(a1, b, acc[1][nf], 0, 0, 0);
    }
  }
#pragma unroll
  for (int gi = 0; gi < 2; ++gi) {
#pragma unroll
    for (int i = 0; i < 4; ++i) {
      long tok = tok0 + gi * 16 + q * 4 + i;
      int bidx = (int)(tok >> 12);
      int n = (int)(tok & (NN - 1));
#pragma unroll
      for (int j = 0; j < 4; ++j) {
        int h = lr + 16 * j;
        float gi_ = acc[gi][j][i] + bias[h];
        float gf_ = acc[gi][j + 4][i] + bias[h + 64];
        float go_ = acc[gi][j + 8][i] + bias[h + 128];
        float gg_ = acc[gi][j + 12][i] + bias[h + 192];
        float cp = c_pre[tok * 64 + h];
        float ig = 1.f / (1.f + __expf(-gi_));
        float fg = 1.f / (1.f + __expf(-gf_));
        float og = 1.f / (1.f + __expf(-go_));
        float ct = fg * cp + ig * tanhf(gg_);
        float ht = og * tanhf(ct);
        c_out[tok * 64 + h] = ct;
        h_out[tok * 64 + h] = ht;
        if (WH2) h_out2[tok * 64 + h] = ht;
        if (WBF) h_bf[((long)(bidx * 128 + h)) * NN + n] = f2bf(ht);
      }
    }
  }
}

extern "C" void kernel_launch(void* const* d_in, const int* in_sizes, int n_in,
                              void* d_out, int out_size, void* d_ws, size_t ws_size,
                              hipStream_t stream) {
  const float* G  = (const float*)d_in[0];
  const float* x_t = (const float*)d_in[1];
  const float* h0 = (const float*)d_in[2];
  const float* h1 = (const float*)d_in[3];
  const float* c0 = (const float*)d_in[4];
  const float* c1 = (const float*)d_in[5];
  const float* W0 = (const float*)d_in[6];
  const float* b0 = (const float*)d_in[7];
  const float* W1 = (const float*)d_in[8];
  const float* b1 = (const float*)d_in[9];
  float* out = (float*)d_out;
  const long M = 8388608L;  // B*N*H

  char* ws = (char*)d_ws;
  unsigned short* Gb    = (unsigned short*)(ws);               // 100,663,296 B
  unsigned short* c0T   = (unsigned short*)(ws + 100663296L);  //  20,971,520 B
  unsigned short* c1T   = (unsigned short*)(ws + 121634816L);  //  33,554,432 B
  unsigned short* supp1 = (unsigned short*)(ws + 155189248L);  // 100,663,296 B
  unsigned short* supp0 = supp1;  // aliased (dead before gemm1 writes)
  unsigned short* Wt0   = (unsigned short*)(ws + 255852544L);
  unsigned short* Wt1   = (unsigned short*)(ws + 255983616L);

  // zero layer-0 supp pad cols only (4 MB instead of 64 MB memset)
  pad_zero<<<1024, 256, 0, stream>>>(supp0);

  cvt_kernel<<<49152, 256, 0, stream>>>(G, Gb, 12582912L);
  pack_comb0<<<dim3(64, 32), 256, 0, stream>>>(x_t, h0, c0T);
  pack_h1<<<dim3(64, 32), 256, 0, stream>>>(h1, c1T);
  prep_wt<<<dim3(256), 256, 0, stream>>>(W0, Wt0, 240, 256);
  prep_wt<<<dim3(256), 256, 0, stream>>>(W1, Wt1, 384, 384);

  // layer 0: 16 bm x 10 bc x 3 kh = 480 blocks; RPK = 20 ranks per kh
  gemm_flow<80, 256, 20><<<480, 512, 0, stream>>>(Gb, c0T, supp0);
  gates_cell<256, true, false><<<1024, 256, 0, stream>>>(
      supp0, Wt0, b0, c0, out + M, out + 3 * M, nullptr, c1T);
  // layer 1: 16 bm x 16 bc x 3 kh = 768 blocks; RPK = 32
  gemm_flow<128, 384, 32><<<768, 512, 0, stream>>>(Gb, c1T, supp1);
  gates_cell<384, false, true><<<1024, 256, 0, stream>>>(
      supp1, Wt1, b1, c1, out, out + 4 * M, out + 2 * M, nullptr);
}